// Round 14
// baseline (158.586 us; speedup 1.0000x reference)
//
#include <hip/hip_runtime.h>
#include <hip/hip_bf16.h>

#define N_NODES 100000
#define N_EDGES 1600000
#define DIM 128

#define NBIN 512          // row partitions
#define RPP  196          // rows per partition (196*511 >= 100000)
#define PCAP 4096         // slab capacity per partition (mean 3125)
#define P1_BLOCKS 512
#define CHUNK (N_EDGES / P1_BLOCKS)   // 3125 edges per pass-1 block

typedef unsigned int uint_t;
typedef unsigned short ushort_t;
typedef float f32x4 __attribute__((ext_vector_type(4)));
typedef __bf16 bf16x8 __attribute__((ext_vector_type(8)));

// fp32 -> bf16 round-to-nearest-even
__device__ inline uint_t f2bf(float f) {
    uint_t u = __float_as_uint(f);
    return (u + 0x7FFFu + ((u >> 16) & 1u)) >> 16;
}
__device__ inline float bf2f(uint_t lo16) { return __uint_as_float(lo16 << 16); }

// ---------------- k1: pass1 (blocks 0..511) + WT build (blocks 512..575) ----------
__global__ __launch_bounds__(256) void pass1_wt(
        const int* __restrict__ rows, const int* __restrict__ cols,
        const float* __restrict__ vals, int* __restrict__ psize,
        long long* __restrict__ slab,
        const float* __restrict__ W0, const float* __restrict__ W1,
        const float* __restrict__ W2, ushort_t* __restrict__ WT) {
    if (blockIdx.x >= P1_BLOCKS) {
        int i = (blockIdx.x - P1_BLOCKS) * 256 + threadIdx.x;   // < 16384
        int m = i & 127, k = i >> 7;
        float s = W0[k * DIM + m] + W1[k * DIM + m] + W2[k * DIM + m];
        WT[m * DIM + k] = (ushort_t)f2bf(s);      // transposed bf16 (32 KB)
        return;
    }
    __shared__ int hist[NBIN];
    __shared__ int binoff[NBIN];
    __shared__ int resv[NBIN];
    __shared__ int curs[NBIN];
    __shared__ long long ebuf[CHUNK];  // 25 KB
    __shared__ int edest[CHUNK];       // 12.5 KB

    int t = threadIdx.x;
    int e0 = blockIdx.x * CHUNK;

    for (int i = t; i < NBIN; i += 256) hist[i] = 0;
    __syncthreads();

    for (int i = t; i < CHUNK; i += 256) {
        int r = rows[e0 + i];
        atomicAdd(&hist[r / RPP], 1);
    }
    __syncthreads();

    if (t < 64) {
        int b = t * 8;
        int v[8]; int s = 0;
#pragma unroll
        for (int k = 0; k < 8; ++k) { v[k] = hist[b + k]; s += v[k]; }
        int incl = s;
#pragma unroll
        for (int d = 1; d < 64; d <<= 1) {
            int o = __shfl_up(incl, d, 64);
            if (t >= d) incl += o;
        }
        int run = incl - s;
#pragma unroll
        for (int k = 0; k < 8; ++k) { binoff[b + k] = run; run += v[k]; }
    }
    __syncthreads();

    for (int i = t; i < NBIN; i += 256) {
        int len = hist[i];
        int r = (len > 0) ? atomicAdd(&psize[i], len) : 0;
        resv[i] = i * PCAP + r;
        curs[i] = binoff[i];
    }
    __syncthreads();

    for (int i = t; i < CHUNK; i += 256) {
        int   r = rows[e0 + i];
        int   c = cols[e0 + i];
        float v = vals[e0 + i];
        int b  = r / RPP;
        int lr = r - b * RPP;
        int pos = atomicAdd(&curs[b], 1);
        uint_t key = ((uint_t)lr << 17) | (uint_t)c;
        ebuf[pos]  = ((long long)__float_as_int(v) << 32) | (long long)key;
        edest[pos] = resv[b] + (pos - binoff[b]);
    }
    __syncthreads();

    for (int i = t; i < CHUNK; i += 256)
        slab[edest[i]] = ebuf[i];
}

// ---------------- k2: fused pass2 (sort) || gemm (MFMA) ---------------------------
// Role-split blocks, 1:3 pass2:gemm interleave; union LDS 36.4 KB -> 4 blocks/CU.
#define GROWS 64
#define XSTR 136   // bf16 per row (128 + 8 pad)
#define SM_INTS 4412          // pb(513)+cnt(197)+loff(197)+curs(196) ints
#define SM_EBUF 4416          // 16B-aligned ebuf offset

__global__ __launch_bounds__(256) void fused_p2_gemm(
        const long long* __restrict__ slab, const int* __restrict__ psize,
        int* __restrict__ off, long long* __restrict__ csr,
        const float* __restrict__ x, const float* __restrict__ oh,
        const ushort_t* __restrict__ WT, uint_t* __restrict__ H16) {
    __shared__ __align__(16) char smem[SM_EBUF + PCAP * 8];  // 37184 B

    int role, idx;
    if (blockIdx.x < 2048) {
        int g = blockIdx.x >> 2, sb = blockIdx.x & 3;
        if (sb == 3) { role = 1; idx = g; }            // pass2: 512 blocks
        else         { role = 0; idx = g * 3 + sb; }   // gemm: 0..1535
    } else {
        role = 0; idx = 1536 + (int)(blockIdx.x - 2048);  // gemm: 1536..1562
    }
    int t = threadIdx.x;

    if (role == 1) {
        // ---------------- pass2: per-partition LDS counting sort --------------
        int* pb   = (int*)smem;                 // 513
        int* cnt  = pb + NBIN + 1;              // 197
        int* loff = cnt + RPP + 1;              // 197
        int* curs = loff + RPP + 1;             // 196
        long long* ebuf = (long long*)(smem + SM_EBUF);   // 32 KB

        int p = idx;

        if (t < 64) {
            int b = t * 8;
            int v[8]; int s = 0;
#pragma unroll
            for (int k = 0; k < 8; ++k) { v[k] = min(psize[b + k], PCAP); s += v[k]; }
            int incl = s;
#pragma unroll
            for (int d = 1; d < 64; d <<= 1) {
                int o = __shfl_up(incl, d, 64);
                if (t >= d) incl += o;
            }
            int run = incl - s;
#pragma unroll
            for (int k = 0; k < 8; ++k) { pb[b + k] = run; run += v[k]; }
            if (t == 63) pb[NBIN] = incl;
        }
        for (int i = t; i < RPP + 1; i += 256) cnt[i] = 0;
        __syncthreads();

        int n = min(psize[p], PCAP);
        int base = pb[p];
        int rlo = p * RPP;
        int nrows = N_NODES - rlo;
        if (nrows > RPP) nrows = RPP;
        if (nrows < 0) nrows = 0;
        const long long* seg = slab + (long long)p * PCAP;

        if (p == NBIN - 1 && t == 0) off[N_NODES] = pb[NBIN];

        for (int i = t; i < n; i += 256) {
            long long ev = __builtin_nontemporal_load(&seg[i]);
            ebuf[i] = ev;
            uint_t key = (uint_t)(ev & 0xFFFFFFFFll);
            atomicAdd(&cnt[key >> 17], 1);
        }
        __syncthreads();

        if (t < 64) {
            int b4 = t * 4;
            int v[4]; int s = 0;
#pragma unroll
            for (int k = 0; k < 4; ++k) {
                int idx2 = b4 + k;
                v[k] = (idx2 < RPP) ? cnt[idx2] : 0;
                s += v[k];
            }
            int incl = s;
#pragma unroll
            for (int d = 1; d < 64; d <<= 1) {
                int o = __shfl_up(incl, d, 64);
                if (t >= d) incl += o;
            }
            int run = incl - s;
#pragma unroll
            for (int k = 0; k < 4; ++k) {
                int idx2 = b4 + k;
                if (idx2 < RPP) loff[idx2] = run;
                run += v[k];
            }
        }
        __syncthreads();

        for (int i = t; i < nrows; i += 256) {
            curs[i] = loff[i];
            off[rlo + i] = base + loff[i];
        }
        __syncthreads();

        for (int i = t; i < n; i += 256) {
            long long ev = ebuf[i];
            uint_t key = (uint_t)(ev & 0xFFFFFFFFll);
            int lr = key >> 17;
            uint_t c = key & 0x1FFFFu;
            int pos = atomicAdd(&curs[lr], 1);
            csr[base + pos] = (long long)(((unsigned long long)ev & 0xFFFFFFFF00000000ull) | c);
        }
    } else {
        // ---------------- gemm: LDS-staged coalesced MFMA ---------------------
        ushort_t* xs = (ushort_t*)smem;      // 17408 B

        int wv = t >> 6, l = t & 63;
        int lr = l & 15, kg = l >> 4;
        int lrow = wv * 16 + lr;
        long long base_row = (long long)idx * GROWS;
        long long hr = base_row + lrow;

        const f32x4* xg = (const f32x4*)x;
#pragma unroll
        for (int i = 0; i < 8; ++i) {
            int g = t + i * 256;
            int row = g >> 5, c4 = g & 31;
            long long sr = base_row + row; if (sr >= N_NODES) sr = N_NODES - 1;
            f32x4 v = __builtin_nontemporal_load(xg + sr * 32 + c4);
            ushort_t* d = &xs[row * XSTR + c4 * 4];
            d[0] = (ushort_t)f2bf(v.x); d[1] = (ushort_t)f2bf(v.y);
            d[2] = (ushort_t)f2bf(v.z); d[3] = (ushort_t)f2bf(v.w);
        }
        __syncthreads();

        f32x4 acc[8] = {};
#pragma unroll
        for (int s = 0; s < 4; ++s) {
            bf16x8 b = *(const bf16x8*)&xs[lrow * XSTR + s * 32 + kg * 8];
#pragma unroll
            for (int mt = 0; mt < 8; ++mt) {
                bf16x8 a = *(const bf16x8*)&WT[(mt * 16 + lr) * DIM + s * 32 + kg * 8];
                acc[mt] = __builtin_amdgcn_mfma_f32_16x16x32_bf16(a, b, acc[mt], 0, 0, 0);
            }
        }
        __syncthreads();

        const f32x4* og = (const f32x4*)oh;
#pragma unroll
        for (int i = 0; i < 8; ++i) {
            int g = t + i * 256;
            int row = g >> 5, c4 = g & 31;
            long long sr = base_row + row; if (sr >= N_NODES) sr = N_NODES - 1;
            f32x4 v = __builtin_nontemporal_load(og + sr * 32 + c4);
            ushort_t* d = &xs[row * XSTR + c4 * 4];
            d[0] = (ushort_t)f2bf(v.x); d[1] = (ushort_t)f2bf(v.y);
            d[2] = (ushort_t)f2bf(v.z); d[3] = (ushort_t)f2bf(v.w);
        }
        __syncthreads();

        if (hr < N_NODES) {
#pragma unroll
            for (int mt = 0; mt < 8; ++mt) {
                int c0 = mt * 16 + kg * 4;
                const uint_t* ow = (const uint_t*)&xs[lrow * XSTR + c0];
                uint_t w0 = ow[0], w1 = ow[1];
                float f0 = acc[mt].x + bf2f(w0 & 0xFFFFu);
                float f1 = acc[mt].y + bf2f(w0 >> 16);
                float f2 = acc[mt].z + bf2f(w1 & 0xFFFFu);
                float f3 = acc[mt].w + bf2f(w1 >> 16);
                uint2 pk;
                pk.x = f2bf(f0) | (f2bf(f1) << 16);
                pk.y = f2bf(f2) | (f2bf(f3) << 16);
                *(uint2*)&H16[(size_t)hr * (DIM / 2) + c0 / 2] = pk;
            }
        }
    }
}

// ---------------- Gather: 4 rows/wave, 16 lanes/row, 4-deep MLP (round-9) ---------
__global__ __launch_bounds__(256) void gather_kernel(const uint_t* __restrict__ H16,
                                                     const int* __restrict__ off,
                                                     const long long* __restrict__ csr,
                                                     float* __restrict__ out) {
    int tid  = threadIdx.x;
    int wave = tid >> 6;
    int lane = tid & 63;
    int grp  = lane >> 4;
    int il   = lane & 15;
    int wid  = blockIdx.x * 16 + wave * 4 + grp;

    int s = off[wid], e = off[wid + 1];
    float acc[8] = {};

#define ACC8(h, v)                                                            \
    acc[0] += (v) * bf2f((h).x & 0xFFFFu); acc[1] += (v) * bf2f((h).x >> 16); \
    acc[2] += (v) * bf2f((h).y & 0xFFFFu); acc[3] += (v) * bf2f((h).y >> 16); \
    acc[4] += (v) * bf2f((h).z & 0xFFFFu); acc[5] += (v) * bf2f((h).z >> 16); \
    acc[6] += (v) * bf2f((h).w & 0xFFFFu); acc[7] += (v) * bf2f((h).w >> 16);

    int p = s;
    for (; p + 3 < e; p += 4) {
        long long cv0 = __builtin_nontemporal_load(&csr[p]);
        long long cv1 = __builtin_nontemporal_load(&csr[p + 1]);
        long long cv2 = __builtin_nontemporal_load(&csr[p + 2]);
        long long cv3 = __builtin_nontemporal_load(&csr[p + 3]);
        uint4 h0 = *(const uint4*)&H16[(long long)(int)(cv0 & 0x1FFFF) * (DIM / 2) + il * 4];
        uint4 h1 = *(const uint4*)&H16[(long long)(int)(cv1 & 0x1FFFF) * (DIM / 2) + il * 4];
        uint4 h2 = *(const uint4*)&H16[(long long)(int)(cv2 & 0x1FFFF) * (DIM / 2) + il * 4];
        uint4 h3 = *(const uint4*)&H16[(long long)(int)(cv3 & 0x1FFFF) * (DIM / 2) + il * 4];
        float v0 = __int_as_float((int)(cv0 >> 32));
        float v1 = __int_as_float((int)(cv1 >> 32));
        float v2 = __int_as_float((int)(cv2 >> 32));
        float v3 = __int_as_float((int)(cv3 >> 32));
        ACC8(h0, v0) ACC8(h1, v1) ACC8(h2, v2) ACC8(h3, v3)
    }
    for (; p < e; ++p) {
        long long cv = __builtin_nontemporal_load(&csr[p]);
        float v = __int_as_float((int)(cv >> 32));
        uint4 h = *(const uint4*)&H16[(long long)(int)(cv & 0x1FFFF) * (DIM / 2) + il * 4];
        ACC8(h, v)
    }
#undef ACC8

    float* op = &out[(long long)wid * DIM + il * 8];
    f32x4 o0 = {acc[0], acc[1], acc[2], acc[3]};
    f32x4 o1 = {acc[4], acc[5], acc[6], acc[7]};
    __builtin_nontemporal_store(o0, (f32x4*)op);
    __builtin_nontemporal_store(o1, (f32x4*)(op + 4));
}

extern "C" void kernel_launch(void* const* d_in, const int* in_sizes, int n_in,
                              void* d_out, int out_size, void* d_ws, size_t ws_size,
                              hipStream_t stream) {
    const float* x    = (const float*)d_in[0];
    const float* oh   = (const float*)d_in[1];
    const float* W0   = (const float*)d_in[2];
    const float* W1   = (const float*)d_in[3];
    const float* W2   = (const float*)d_in[4];
    const int*   rows = (const int*)d_in[5];
    const int*   cols = (const int*)d_in[6];
    const float* vals = (const float*)d_in[7];
    float* out = (float*)d_out;

    // workspace layout
    char* p = (char*)d_ws;
    size_t oW    = 0;                                   // WsumT bf16: 32 KB (64 KB reserved)
    size_t oH    = oW + 64 * 1024;                      // H bf16: 25.6 MB
    size_t oOff  = oH + (size_t)N_NODES * DIM * 2;      // off: N_NODES+1 (+pad)
    size_t oPs   = oOff + (size_t)(N_NODES + 32) * 4;   // psize: 512 ints
    size_t oSlab = oPs + 4096;                          // slabs: 512*4096*8B = 16.8 MB
    size_t oCsr  = oSlab + (size_t)NBIN * PCAP * 8;     // csr: 12.8 MB

    ushort_t*  WT    = (ushort_t*)(p + oW);
    uint_t*    H16   = (uint_t*)(p + oH);
    int*       off   = (int*)(p + oOff);
    int*       psize = (int*)(p + oPs);
    long long* slab  = (long long*)(p + oSlab);
    long long* csr   = (long long*)(p + oCsr);

    (void)hipMemsetAsync(psize, 0, NBIN * sizeof(int), stream);
    pass1_wt<<<P1_BLOCKS + 64, 256, 0, stream>>>(rows, cols, vals, psize, slab,
                                                 W0, W1, W2, WT);
    fused_p2_gemm<<<2075, 256, 0, stream>>>(slab, psize, off, csr, x, oh, WT, H16);
    gather_kernel<<<N_NODES / 16, 256, 0, stream>>>(H16, off, csr, out);
}

// Round 15
// 155.340 us; speedup vs baseline: 1.0209x; 1.0209x over previous
//
#include <hip/hip_runtime.h>
#include <hip/hip_bf16.h>

#define N_NODES 100000
#define N_EDGES 1600000
#define DIM 128

#define NBIN 512          // row partitions
#define RPP  196          // rows per partition
#define PCAP 4096         // slab capacity per partition (mean 3125)
#define P1_BLOCKS 512
#define CHUNK (N_EDGES / P1_BLOCKS)   // 3125 edges per pass-1 block

#define GEMM_TOTAL 1563   // ceil(100000/64)
#define GEMM_A 782        // rows 0..50047 in k1
#define GEMM_B 781        // rows 50048.. in k2

typedef unsigned int uint_t;
typedef unsigned short ushort_t;
typedef float f32x4 __attribute__((ext_vector_type(4)));
typedef __bf16 bf16x8 __attribute__((ext_vector_type(8)));

__device__ inline uint_t f2bf(float f) {
    uint_t u = __float_as_uint(f);
    return (u + 0x7FFFu + ((u >> 16) & 1u)) >> 16;
}
__device__ inline float bf2f(uint_t lo16) { return __uint_as_float(lo16 << 16); }

// ---------------- k0: WT build (blocks 0..63) + psize zero (block 64) -------------
__global__ __launch_bounds__(256) void wt_init(const float* __restrict__ W0,
                                               const float* __restrict__ W1,
                                               const float* __restrict__ W2,
                                               ushort_t* __restrict__ WT,
                                               int* __restrict__ psize) {
    if (blockIdx.x == 64) {
        int i = threadIdx.x;
        if (i < NBIN / 2) ((int2*)psize)[i] = make_int2(0, 0);
        return;
    }
    int i = blockIdx.x * 256 + threadIdx.x;   // < 16384
    int m = i & 127, k = i >> 7;
    float s = W0[k * DIM + m] + W1[k * DIM + m] + W2[k * DIM + m];
    WT[m * DIM + k] = (ushort_t)f2bf(s);      // transposed bf16 (32 KB)
}

// ---------------- role bodies -----------------------------------------------------
#define GROWS 64
#define XSTR 136   // bf16 per row (128 + 8 pad)

__device__ __forceinline__ void gemm_body(int idx, int t, char* smem,
                                          const float* __restrict__ x,
                                          const float* __restrict__ oh,
                                          const ushort_t* __restrict__ WT,
                                          uint_t* __restrict__ H16) {
    ushort_t* xs = (ushort_t*)smem;      // 17408 B

    int wv = t >> 6, l = t & 63;
    int lr = l & 15, kg = l >> 4;
    int lrow = wv * 16 + lr;
    long long base_row = (long long)idx * GROWS;
    long long hr = base_row + lrow;

    const f32x4* xg = (const f32x4*)x;
#pragma unroll
    for (int i = 0; i < 8; ++i) {
        int g = t + i * 256;
        int row = g >> 5, c4 = g & 31;
        long long sr = base_row + row; if (sr >= N_NODES) sr = N_NODES - 1;
        f32x4 v = __builtin_nontemporal_load(xg + sr * 32 + c4);
        ushort_t* d = &xs[row * XSTR + c4 * 4];
        d[0] = (ushort_t)f2bf(v.x); d[1] = (ushort_t)f2bf(v.y);
        d[2] = (ushort_t)f2bf(v.z); d[3] = (ushort_t)f2bf(v.w);
    }
    __syncthreads();

    f32x4 acc[8] = {};
#pragma unroll
    for (int s = 0; s < 4; ++s) {
        bf16x8 b = *(const bf16x8*)&xs[lrow * XSTR + s * 32 + kg * 8];
#pragma unroll
        for (int mt = 0; mt < 8; ++mt) {
            bf16x8 a = *(const bf16x8*)&WT[(mt * 16 + lr) * DIM + s * 32 + kg * 8];
            acc[mt] = __builtin_amdgcn_mfma_f32_16x16x32_bf16(a, b, acc[mt], 0, 0, 0);
        }
    }
    __syncthreads();

    const f32x4* og = (const f32x4*)oh;
#pragma unroll
    for (int i = 0; i < 8; ++i) {
        int g = t + i * 256;
        int row = g >> 5, c4 = g & 31;
        long long sr = base_row + row; if (sr >= N_NODES) sr = N_NODES - 1;
        f32x4 v = __builtin_nontemporal_load(og + sr * 32 + c4);
        ushort_t* d = &xs[row * XSTR + c4 * 4];
        d[0] = (ushort_t)f2bf(v.x); d[1] = (ushort_t)f2bf(v.y);
        d[2] = (ushort_t)f2bf(v.z); d[3] = (ushort_t)f2bf(v.w);
    }
    __syncthreads();

    if (hr < N_NODES) {
#pragma unroll
        for (int mt = 0; mt < 8; ++mt) {
            int c0 = mt * 16 + kg * 4;
            const uint_t* ow = (const uint_t*)&xs[lrow * XSTR + c0];
            uint_t w0 = ow[0], w1 = ow[1];
            float f0 = acc[mt].x + bf2f(w0 & 0xFFFFu);
            float f1 = acc[mt].y + bf2f(w0 >> 16);
            float f2 = acc[mt].z + bf2f(w1 & 0xFFFFu);
            float f3 = acc[mt].w + bf2f(w1 >> 16);
            uint2 pk;
            pk.x = f2bf(f0) | (f2bf(f1) << 16);
            pk.y = f2bf(f2) | (f2bf(f3) << 16);
            *(uint2*)&H16[(size_t)hr * (DIM / 2) + c0 / 2] = pk;
        }
    }
}

__device__ __forceinline__ void pass1_body(int idx, int t, char* smem,
                                           const int* __restrict__ rows,
                                           const int* __restrict__ cols,
                                           const float* __restrict__ vals,
                                           int* __restrict__ psize,
                                           long long* __restrict__ slab) {
    int* hist   = (int*)smem;            // 2 KB
    int* binoff = hist + NBIN;           // 2 KB
    int* resv   = binoff + NBIN;         // 2 KB
    int* curs   = resv + NBIN;           // 2 KB
    long long* ebuf = (long long*)(smem + 8192);          // 25 KB
    int* edest  = (int*)(smem + 8192 + CHUNK * 8);        // 12.5 KB

    int e0 = idx * CHUNK;

    for (int i = t; i < NBIN; i += 256) hist[i] = 0;
    __syncthreads();

    for (int i = t; i < CHUNK; i += 256) {
        int r = rows[e0 + i];
        atomicAdd(&hist[r / RPP], 1);
    }
    __syncthreads();

    if (t < 64) {
        int b = t * 8;
        int v[8]; int s = 0;
#pragma unroll
        for (int k = 0; k < 8; ++k) { v[k] = hist[b + k]; s += v[k]; }
        int incl = s;
#pragma unroll
        for (int d = 1; d < 64; d <<= 1) {
            int o = __shfl_up(incl, d, 64);
            if (t >= d) incl += o;
        }
        int run = incl - s;
#pragma unroll
        for (int k = 0; k < 8; ++k) { binoff[b + k] = run; run += v[k]; }
    }
    __syncthreads();

    for (int i = t; i < NBIN; i += 256) {
        int len = hist[i];
        int r = (len > 0) ? atomicAdd(&psize[i], len) : 0;
        resv[i] = i * PCAP + r;
        curs[i] = binoff[i];
    }
    __syncthreads();

    for (int i = t; i < CHUNK; i += 256) {
        int   r = rows[e0 + i];
        int   c = cols[e0 + i];
        float v = vals[e0 + i];
        int b  = r / RPP;
        int lr = r - b * RPP;
        int pos = atomicAdd(&curs[b], 1);
        uint_t key = ((uint_t)lr << 17) | (uint_t)c;
        ebuf[pos]  = ((long long)__float_as_int(v) << 32) | (long long)key;
        edest[pos] = resv[b] + (pos - binoff[b]);
    }
    __syncthreads();

    for (int i = t; i < CHUNK; i += 256)
        slab[edest[i]] = ebuf[i];
}

#define SM_EBUF 4416          // 16B-aligned ebuf offset for pass2

__device__ __forceinline__ void pass2_body(int p, int t, char* smem,
                                           const long long* __restrict__ slab,
                                           const int* __restrict__ psize,
                                           int* __restrict__ off,
                                           long long* __restrict__ csr) {
    int* pb   = (int*)smem;                 // 513
    int* cnt  = pb + NBIN + 1;              // 197
    int* loff = cnt + RPP + 1;              // 197
    int* curs = loff + RPP + 1;             // 196
    long long* ebuf = (long long*)(smem + SM_EBUF);   // 32 KB

    if (t < 64) {
        int b = t * 8;
        int v[8]; int s = 0;
#pragma unroll
        for (int k = 0; k < 8; ++k) { v[k] = min(psize[b + k], PCAP); s += v[k]; }
        int incl = s;
#pragma unroll
        for (int d = 1; d < 64; d <<= 1) {
            int o = __shfl_up(incl, d, 64);
            if (t >= d) incl += o;
        }
        int run = incl - s;
#pragma unroll
        for (int k = 0; k < 8; ++k) { pb[b + k] = run; run += v[k]; }
        if (t == 63) pb[NBIN] = incl;
    }
    for (int i = t; i < RPP + 1; i += 256) cnt[i] = 0;
    __syncthreads();

    int n = min(psize[p], PCAP);
    int base = pb[p];
    int rlo = p * RPP;
    int nrows = N_NODES - rlo;
    if (nrows > RPP) nrows = RPP;
    if (nrows < 0) nrows = 0;
    const long long* seg = slab + (long long)p * PCAP;

    if (p == NBIN - 1 && t == 0) off[N_NODES] = pb[NBIN];

    for (int i = t; i < n; i += 256) {
        long long ev = __builtin_nontemporal_load(&seg[i]);
        ebuf[i] = ev;
        uint_t key = (uint_t)(ev & 0xFFFFFFFFll);
        atomicAdd(&cnt[key >> 17], 1);
    }
    __syncthreads();

    if (t < 64) {
        int b4 = t * 4;
        int v[4]; int s = 0;
#pragma unroll
        for (int k = 0; k < 4; ++k) {
            int idx2 = b4 + k;
            v[k] = (idx2 < RPP) ? cnt[idx2] : 0;
            s += v[k];
        }
        int incl = s;
#pragma unroll
        for (int d = 1; d < 64; d <<= 1) {
            int o = __shfl_up(incl, d, 64);
            if (t >= d) incl += o;
        }
        int run = incl - s;
#pragma unroll
        for (int k = 0; k < 4; ++k) {
            int idx2 = b4 + k;
            if (idx2 < RPP) loff[idx2] = run;
            run += v[k];
        }
    }
    __syncthreads();

    for (int i = t; i < nrows; i += 256) {
        curs[i] = loff[i];
        off[rlo + i] = base + loff[i];
    }
    __syncthreads();

    for (int i = t; i < n; i += 256) {
        long long ev = ebuf[i];
        uint_t key = (uint_t)(ev & 0xFFFFFFFFll);
        int lr = key >> 17;
        uint_t c = key & 0x1FFFFu;
        int pos = atomicAdd(&curs[lr], 1);
        csr[base + pos] = (long long)(((unsigned long long)ev & 0xFFFFFFFF00000000ull) | c);
    }
}

// ---------------- k1: pass1 || gemm rows 0..GEMM_A*64 -----------------------------
__global__ __launch_bounds__(256) void fused_p1_gemmA(
        const int* __restrict__ rows, const int* __restrict__ cols,
        const float* __restrict__ vals, int* __restrict__ psize,
        long long* __restrict__ slab,
        const float* __restrict__ x, const float* __restrict__ oh,
        const ushort_t* __restrict__ WT, uint_t* __restrict__ H16) {
    __shared__ __align__(16) char smem[8192 + CHUNK * 8 + CHUNK * 4];  // 45692 B
    int bid = blockIdx.x, t = threadIdx.x;
    if (bid < 1280) {
        int g = bid / 5, sb = bid - g * 5;
        if (sb < 2) pass1_body(g * 2 + sb, t, smem, rows, cols, vals, psize, slab);
        else        gemm_body(g * 3 + (sb - 2), t, smem, x, oh, WT, H16);
    } else {
        gemm_body(768 + (bid - 1280), t, smem, x, oh, WT, H16);  // 768..781
    }
}

// ---------------- k2: pass2 || gemm rows GEMM_A*64.. ------------------------------
__global__ __launch_bounds__(256) void fused_p2_gemmB(
        const long long* __restrict__ slab, const int* __restrict__ psize,
        int* __restrict__ off, long long* __restrict__ csr,
        const float* __restrict__ x, const float* __restrict__ oh,
        const ushort_t* __restrict__ WT, uint_t* __restrict__ H16) {
    __shared__ __align__(16) char smem[SM_EBUF + PCAP * 8];  // 37184 B
    int bid = blockIdx.x, t = threadIdx.x;
    if (bid < 1280) {
        int g = bid / 5, sb = bid - g * 5;
        if (sb < 2) pass2_body(g * 2 + sb, t, smem, slab, psize, off, csr);
        else        gemm_body(GEMM_A + g * 3 + (sb - 2), t, smem, x, oh, WT, H16);
    } else {
        gemm_body(GEMM_A + 768 + (bid - 1280), t, smem, x, oh, WT, H16);  // ..1562
    }
}

// ---------------- Gather: 4 rows/wave, 16 lanes/row, 4-deep MLP (round-9) ---------
__global__ __launch_bounds__(256) void gather_kernel(const uint_t* __restrict__ H16,
                                                     const int* __restrict__ off,
                                                     const long long* __restrict__ csr,
                                                     float* __restrict__ out) {
    int tid  = threadIdx.x;
    int wave = tid >> 6;
    int lane = tid & 63;
    int grp  = lane >> 4;
    int il   = lane & 15;
    int wid  = blockIdx.x * 16 + wave * 4 + grp;

    int s = off[wid], e = off[wid + 1];
    float acc[8] = {};

#define ACC8(h, v)                                                            \
    acc[0] += (v) * bf2f((h).x & 0xFFFFu); acc[1] += (v) * bf2f((h).x >> 16); \
    acc[2] += (v) * bf2f((h).y & 0xFFFFu); acc[3] += (v) * bf2f((h).y >> 16); \
    acc[4] += (v) * bf2f((h).z & 0xFFFFu); acc[5] += (v) * bf2f((h).z >> 16); \
    acc[6] += (v) * bf2f((h).w & 0xFFFFu); acc[7] += (v) * bf2f((h).w >> 16);

    int p = s;
    for (; p + 3 < e; p += 4) {
        long long cv0 = __builtin_nontemporal_load(&csr[p]);
        long long cv1 = __builtin_nontemporal_load(&csr[p + 1]);
        long long cv2 = __builtin_nontemporal_load(&csr[p + 2]);
        long long cv3 = __builtin_nontemporal_load(&csr[p + 3]);
        uint4 h0 = *(const uint4*)&H16[(long long)(int)(cv0 & 0x1FFFF) * (DIM / 2) + il * 4];
        uint4 h1 = *(const uint4*)&H16[(long long)(int)(cv1 & 0x1FFFF) * (DIM / 2) + il * 4];
        uint4 h2 = *(const uint4*)&H16[(long long)(int)(cv2 & 0x1FFFF) * (DIM / 2) + il * 4];
        uint4 h3 = *(const uint4*)&H16[(long long)(int)(cv3 & 0x1FFFF) * (DIM / 2) + il * 4];
        float v0 = __int_as_float((int)(cv0 >> 32));
        float v1 = __int_as_float((int)(cv1 >> 32));
        float v2 = __int_as_float((int)(cv2 >> 32));
        float v3 = __int_as_float((int)(cv3 >> 32));
        ACC8(h0, v0) ACC8(h1, v1) ACC8(h2, v2) ACC8(h3, v3)
    }
    for (; p < e; ++p) {
        long long cv = __builtin_nontemporal_load(&csr[p]);
        float v = __int_as_float((int)(cv >> 32));
        uint4 h = *(const uint4*)&H16[(long long)(int)(cv & 0x1FFFF) * (DIM / 2) + il * 4];
        ACC8(h, v)
    }
#undef ACC8

    float* op = &out[(long long)wid * DIM + il * 8];
    f32x4 o0 = {acc[0], acc[1], acc[2], acc[3]};
    f32x4 o1 = {acc[4], acc[5], acc[6], acc[7]};
    __builtin_nontemporal_store(o0, (f32x4*)op);
    __builtin_nontemporal_store(o1, (f32x4*)(op + 4));
}

extern "C" void kernel_launch(void* const* d_in, const int* in_sizes, int n_in,
                              void* d_out, int out_size, void* d_ws, size_t ws_size,
                              hipStream_t stream) {
    const float* x    = (const float*)d_in[0];
    const float* oh   = (const float*)d_in[1];
    const float* W0   = (const float*)d_in[2];
    const float* W1   = (const float*)d_in[3];
    const float* W2   = (const float*)d_in[4];
    const int*   rows = (const int*)d_in[5];
    const int*   cols = (const int*)d_in[6];
    const float* vals = (const float*)d_in[7];
    float* out = (float*)d_out;

    // workspace layout
    char* p = (char*)d_ws;
    size_t oW    = 0;                                   // WsumT bf16: 32 KB (64 KB reserved)
    size_t oH    = oW + 64 * 1024;                      // H bf16: 25.6 MB
    size_t oOff  = oH + (size_t)N_NODES * DIM * 2;      // off: N_NODES+1 (+pad)
    size_t oPs   = oOff + (size_t)(N_NODES + 32) * 4;   // psize: 512 ints
    size_t oSlab = oPs + 4096;                          // slabs: 512*4096*8B = 16.8 MB
    size_t oCsr  = oSlab + (size_t)NBIN * PCAP * 8;     // csr: 12.8 MB

    ushort_t*  WT    = (ushort_t*)(p + oW);
    uint_t*    H16   = (uint_t*)(p + oH);
    int*       off   = (int*)(p + oOff);
    int*       psize = (int*)(p + oPs);
    long long* slab  = (long long*)(p + oSlab);
    long long* csr   = (long long*)(p + oCsr);

    wt_init<<<65, 256, 0, stream>>>(W0, W1, W2, WT, psize);
    fused_p1_gemmA<<<1294, 256, 0, stream>>>(rows, cols, vals, psize, slab,
                                             x, oh, WT, H16);
    fused_p2_gemmB<<<1293, 256, 0, stream>>>(slab, psize, off, csr,
                                             x, oh, WT, H16);
    gather_kernel<<<N_NODES / 16, 256, 0, stream>>>(H16, off, csr, out);
}

// Round 16
// 149.253 us; speedup vs baseline: 1.0625x; 1.0408x over previous
//
#include <hip/hip_runtime.h>
#include <hip/hip_bf16.h>

#define N_NODES 100000
#define N_EDGES 1600000
#define DIM 128

#define NBIN 512          // row partitions
#define RPP  196          // rows per partition (196*511 >= 100000)
#define PCAP 4096         // slab capacity per partition (mean 3125)
#define P1_BLOCKS 512
#define CHUNK (N_EDGES / P1_BLOCKS)   // 3125 edges per pass-1 block

typedef unsigned int uint_t;
typedef unsigned short ushort_t;
typedef float f32x4 __attribute__((ext_vector_type(4)));
typedef __bf16 bf16x8 __attribute__((ext_vector_type(8)));

// fp32 -> bf16 round-to-nearest-even
__device__ inline uint_t f2bf(float f) {
    uint_t u = __float_as_uint(f);
    return (u + 0x7FFFu + ((u >> 16) & 1u)) >> 16;
}
__device__ inline float bf2f(uint_t lo16) { return __uint_as_float(lo16 << 16); }

// ---------------- k0: WT build (blocks 0..63) + psize zero (block 64) -------------
__global__ __launch_bounds__(256) void wt_init(const float* __restrict__ W0,
                                               const float* __restrict__ W1,
                                               const float* __restrict__ W2,
                                               ushort_t* __restrict__ WT,
                                               int* __restrict__ psize) {
    if (blockIdx.x == 64) {
        int i = threadIdx.x;
        if (i < NBIN / 2) ((int2*)psize)[i] = make_int2(0, 0);
        return;
    }
    int i = blockIdx.x * 256 + threadIdx.x;   // < 16384
    int m = i & 127, k = i >> 7;
    float s = W0[k * DIM + m] + W1[k * DIM + m] + W2[k * DIM + m];
    WT[m * DIM + k] = (ushort_t)f2bf(s);      // transposed bf16 (32 KB)
}

// ---------------- k1: fused pass1 (bin) || gemm (MFMA) ----------------------------
// Role-split blocks, 3:1 gemm:pass1 interleave. LDS slimmed to 39.4 KB
// (edest int -> ebin ushort; dest recomputed as resv[b] + (i - binoff[b]))
// -> 4 blocks/CU for both roles.
#define GROWS 64
#define XSTR 136   // bf16 per row (128 + 8 pad)
#define SM_EBUF_OFF 8192
#define SM_EBIN_OFF (8192 + CHUNK * 8)
#define SM_TOTAL (8192 + CHUNK * 8 + CHUNK * 2 + 8)   // 39450 B

__global__ __launch_bounds__(256) void fused_p1_gemm(
        const int* __restrict__ rows, const int* __restrict__ cols,
        const float* __restrict__ vals, int* __restrict__ psize,
        long long* __restrict__ slab,
        const float* __restrict__ x, const float* __restrict__ oh,
        const ushort_t* __restrict__ WT, uint_t* __restrict__ H16) {
    __shared__ __align__(16) char smem[SM_TOTAL];

    int role, idx;
    if (blockIdx.x < 2048) {
        int g = blockIdx.x >> 2, sb = blockIdx.x & 3;
        if (sb == 3) { role = 1; idx = g; }            // pass1: 512 blocks
        else         { role = 0; idx = g * 3 + sb; }   // gemm: 0..1535
    } else {
        role = 0; idx = 1536 + (int)(blockIdx.x - 2048);  // gemm: 1536..1562
    }
    int t = threadIdx.x;

    if (role == 1) {
        // ---------------- pass1: coarse bin into 512 partition slabs ----------
        int* hist   = (int*)smem;            // 2 KB
        int* binoff = hist + NBIN;           // 2 KB
        int* resv   = binoff + NBIN;         // 2 KB
        int* curs   = resv + NBIN;           // 2 KB
        long long* ebuf = (long long*)(smem + SM_EBUF_OFF);   // 25 KB
        ushort_t* ebin  = (ushort_t*)(smem + SM_EBIN_OFF);    // 6.25 KB

        int e0 = idx * CHUNK;

        for (int i = t; i < NBIN; i += 256) hist[i] = 0;
        __syncthreads();

        for (int i = t; i < CHUNK; i += 256) {
            int r = rows[e0 + i];
            atomicAdd(&hist[r / RPP], 1);
        }
        __syncthreads();

        if (t < 64) {
            int b = t * 8;
            int v[8]; int s = 0;
#pragma unroll
            for (int k = 0; k < 8; ++k) { v[k] = hist[b + k]; s += v[k]; }
            int incl = s;
#pragma unroll
            for (int d = 1; d < 64; d <<= 1) {
                int o = __shfl_up(incl, d, 64);
                if (t >= d) incl += o;
            }
            int run = incl - s;
#pragma unroll
            for (int k = 0; k < 8; ++k) { binoff[b + k] = run; run += v[k]; }
        }
        __syncthreads();

        for (int i = t; i < NBIN; i += 256) {
            int len = hist[i];
            int r = (len > 0) ? atomicAdd(&psize[i], len) : 0;
            resv[i] = i * PCAP + r;
            curs[i] = binoff[i];
        }
        __syncthreads();

        for (int i = t; i < CHUNK; i += 256) {
            int   r = rows[e0 + i];
            int   c = cols[e0 + i];
            float v = vals[e0 + i];
            int b  = r / RPP;
            int lr = r - b * RPP;
            int pos = atomicAdd(&curs[b], 1);
            uint_t key = ((uint_t)lr << 17) | (uint_t)c;
            ebuf[pos] = ((long long)__float_as_int(v) << 32) | (long long)key;
            ebin[pos] = (ushort_t)b;
        }
        __syncthreads();

        for (int i = t; i < CHUNK; i += 256) {
            int b = ebin[i];
            slab[resv[b] + (i - binoff[b])] = ebuf[i];
        }
    } else {
        // ---------------- gemm: LDS-staged coalesced MFMA ---------------------
        ushort_t* xs = (ushort_t*)smem;      // 17408 B

        int wv = t >> 6, l = t & 63;
        int lr = l & 15, kg = l >> 4;
        int lrow = wv * 16 + lr;
        long long base_row = (long long)idx * GROWS;
        long long hr = base_row + lrow;

        const f32x4* xg = (const f32x4*)x;
#pragma unroll
        for (int i = 0; i < 8; ++i) {
            int g = t + i * 256;
            int row = g >> 5, c4 = g & 31;
            long long sr = base_row + row; if (sr >= N_NODES) sr = N_NODES - 1;
            f32x4 v = __builtin_nontemporal_load(xg + sr * 32 + c4);
            ushort_t* d = &xs[row * XSTR + c4 * 4];
            d[0] = (ushort_t)f2bf(v.x); d[1] = (ushort_t)f2bf(v.y);
            d[2] = (ushort_t)f2bf(v.z); d[3] = (ushort_t)f2bf(v.w);
        }
        __syncthreads();

        f32x4 acc[8] = {};
#pragma unroll
        for (int s = 0; s < 4; ++s) {
            bf16x8 b = *(const bf16x8*)&xs[lrow * XSTR + s * 32 + kg * 8];
#pragma unroll
            for (int mt = 0; mt < 8; ++mt) {
                bf16x8 a = *(const bf16x8*)&WT[(mt * 16 + lr) * DIM + s * 32 + kg * 8];
                acc[mt] = __builtin_amdgcn_mfma_f32_16x16x32_bf16(a, b, acc[mt], 0, 0, 0);
            }
        }
        __syncthreads();

        const f32x4* og = (const f32x4*)oh;
#pragma unroll
        for (int i = 0; i < 8; ++i) {
            int g = t + i * 256;
            int row = g >> 5, c4 = g & 31;
            long long sr = base_row + row; if (sr >= N_NODES) sr = N_NODES - 1;
            f32x4 v = __builtin_nontemporal_load(og + sr * 32 + c4);
            ushort_t* d = &xs[row * XSTR + c4 * 4];
            d[0] = (ushort_t)f2bf(v.x); d[1] = (ushort_t)f2bf(v.y);
            d[2] = (ushort_t)f2bf(v.z); d[3] = (ushort_t)f2bf(v.w);
        }
        __syncthreads();

        if (hr < N_NODES) {
#pragma unroll
            for (int mt = 0; mt < 8; ++mt) {
                int c0 = mt * 16 + kg * 4;
                const uint_t* ow = (const uint_t*)&xs[lrow * XSTR + c0];
                uint_t w0 = ow[0], w1 = ow[1];
                float f0 = acc[mt].x + bf2f(w0 & 0xFFFFu);
                float f1 = acc[mt].y + bf2f(w0 >> 16);
                float f2 = acc[mt].z + bf2f(w1 & 0xFFFFu);
                float f3 = acc[mt].w + bf2f(w1 >> 16);
                uint2 pk;
                pk.x = f2bf(f0) | (f2bf(f1) << 16);
                pk.y = f2bf(f2) | (f2bf(f3) << 16);
                *(uint2*)&H16[(size_t)hr * (DIM / 2) + c0 / 2] = pk;
            }
        }
    }
}

// ---------------- Pass 2: per-partition LDS counting sort (round-12) --------------
__global__ __launch_bounds__(256) void pass2_sort(
        const long long* __restrict__ slab, const int* __restrict__ psize,
        int* __restrict__ off, long long* __restrict__ csr) {
    __shared__ int pb[NBIN + 1];
    __shared__ int cnt[RPP + 1];
    __shared__ int loff[RPP + 1];
    __shared__ int curs[RPP];
    __shared__ long long ebuf[PCAP];   // 32 KB

    int p = blockIdx.x, t = threadIdx.x;

    if (t < 64) {
        int b = t * 8;
        int v[8]; int s = 0;
#pragma unroll
        for (int k = 0; k < 8; ++k) { v[k] = min(psize[b + k], PCAP); s += v[k]; }
        int incl = s;
#pragma unroll
        for (int d = 1; d < 64; d <<= 1) {
            int o = __shfl_up(incl, d, 64);
            if (t >= d) incl += o;
        }
        int run = incl - s;
#pragma unroll
        for (int k = 0; k < 8; ++k) { pb[b + k] = run; run += v[k]; }
        if (t == 63) pb[NBIN] = incl;
    }
    for (int i = t; i < RPP + 1; i += 256) cnt[i] = 0;
    __syncthreads();

    int n = min(psize[p], PCAP);
    int base = pb[p];
    int rlo = p * RPP;
    int nrows = N_NODES - rlo;
    if (nrows > RPP) nrows = RPP;
    if (nrows < 0) nrows = 0;
    const long long* seg = slab + (long long)p * PCAP;

    if (p == NBIN - 1 && t == 0) off[N_NODES] = pb[NBIN];

    for (int i = t; i < n; i += 256) {
        long long ev = __builtin_nontemporal_load(&seg[i]);
        ebuf[i] = ev;
        uint_t key = (uint_t)(ev & 0xFFFFFFFFll);
        atomicAdd(&cnt[key >> 17], 1);
    }
    __syncthreads();

    if (t < 64) {
        int b4 = t * 4;
        int v[4]; int s = 0;
#pragma unroll
        for (int k = 0; k < 4; ++k) {
            int idx2 = b4 + k;
            v[k] = (idx2 < RPP) ? cnt[idx2] : 0;
            s += v[k];
        }
        int incl = s;
#pragma unroll
        for (int d = 1; d < 64; d <<= 1) {
            int o = __shfl_up(incl, d, 64);
            if (t >= d) incl += o;
        }
        int run = incl - s;
#pragma unroll
        for (int k = 0; k < 4; ++k) {
            int idx2 = b4 + k;
            if (idx2 < RPP) loff[idx2] = run;
            run += v[k];
        }
    }
    __syncthreads();

    for (int i = t; i < nrows; i += 256) {
        curs[i] = loff[i];
        off[rlo + i] = base + loff[i];
    }
    __syncthreads();

    for (int i = t; i < n; i += 256) {
        long long ev = ebuf[i];
        uint_t key = (uint_t)(ev & 0xFFFFFFFFll);
        int lr = key >> 17;
        uint_t c = key & 0x1FFFFu;
        int pos = atomicAdd(&curs[lr], 1);
        csr[base + pos] = (long long)(((unsigned long long)ev & 0xFFFFFFFF00000000ull) | c);
    }
}

// ---------------- Gather: 4 rows/wave, 16 lanes/row, 4-deep MLP (round-9) ---------
__global__ __launch_bounds__(256) void gather_kernel(const uint_t* __restrict__ H16,
                                                     const int* __restrict__ off,
                                                     const long long* __restrict__ csr,
                                                     float* __restrict__ out) {
    int tid  = threadIdx.x;
    int wave = tid >> 6;
    int lane = tid & 63;
    int grp  = lane >> 4;
    int il   = lane & 15;
    int wid  = blockIdx.x * 16 + wave * 4 + grp;

    int s = off[wid], e = off[wid + 1];
    float acc[8] = {};

#define ACC8(h, v)                                                            \
    acc[0] += (v) * bf2f((h).x & 0xFFFFu); acc[1] += (v) * bf2f((h).x >> 16); \
    acc[2] += (v) * bf2f((h).y & 0xFFFFu); acc[3] += (v) * bf2f((h).y >> 16); \
    acc[4] += (v) * bf2f((h).z & 0xFFFFu); acc[5] += (v) * bf2f((h).z >> 16); \
    acc[6] += (v) * bf2f((h).w & 0xFFFFu); acc[7] += (v) * bf2f((h).w >> 16);

    int p = s;
    for (; p + 3 < e; p += 4) {
        long long cv0 = __builtin_nontemporal_load(&csr[p]);
        long long cv1 = __builtin_nontemporal_load(&csr[p + 1]);
        long long cv2 = __builtin_nontemporal_load(&csr[p + 2]);
        long long cv3 = __builtin_nontemporal_load(&csr[p + 3]);
        uint4 h0 = *(const uint4*)&H16[(long long)(int)(cv0 & 0x1FFFF) * (DIM / 2) + il * 4];
        uint4 h1 = *(const uint4*)&H16[(long long)(int)(cv1 & 0x1FFFF) * (DIM / 2) + il * 4];
        uint4 h2 = *(const uint4*)&H16[(long long)(int)(cv2 & 0x1FFFF) * (DIM / 2) + il * 4];
        uint4 h3 = *(const uint4*)&H16[(long long)(int)(cv3 & 0x1FFFF) * (DIM / 2) + il * 4];
        float v0 = __int_as_float((int)(cv0 >> 32));
        float v1 = __int_as_float((int)(cv1 >> 32));
        float v2 = __int_as_float((int)(cv2 >> 32));
        float v3 = __int_as_float((int)(cv3 >> 32));
        ACC8(h0, v0) ACC8(h1, v1) ACC8(h2, v2) ACC8(h3, v3)
    }
    for (; p < e; ++p) {
        long long cv = __builtin_nontemporal_load(&csr[p]);
        float v = __int_as_float((int)(cv >> 32));
        uint4 h = *(const uint4*)&H16[(long long)(int)(cv & 0x1FFFF) * (DIM / 2) + il * 4];
        ACC8(h, v)
    }
#undef ACC8

    float* op = &out[(long long)wid * DIM + il * 8];
    f32x4 o0 = {acc[0], acc[1], acc[2], acc[3]};
    f32x4 o1 = {acc[4], acc[5], acc[6], acc[7]};
    __builtin_nontemporal_store(o0, (f32x4*)op);
    __builtin_nontemporal_store(o1, (f32x4*)(op + 4));
}

extern "C" void kernel_launch(void* const* d_in, const int* in_sizes, int n_in,
                              void* d_out, int out_size, void* d_ws, size_t ws_size,
                              hipStream_t stream) {
    const float* x    = (const float*)d_in[0];
    const float* oh   = (const float*)d_in[1];
    const float* W0   = (const float*)d_in[2];
    const float* W1   = (const float*)d_in[3];
    const float* W2   = (const float*)d_in[4];
    const int*   rows = (const int*)d_in[5];
    const int*   cols = (const int*)d_in[6];
    const float* vals = (const float*)d_in[7];
    float* out = (float*)d_out;

    // workspace layout
    char* p = (char*)d_ws;
    size_t oW    = 0;                                   // WsumT bf16: 32 KB (64 KB reserved)
    size_t oH    = oW + 64 * 1024;                      // H bf16: 25.6 MB
    size_t oOff  = oH + (size_t)N_NODES * DIM * 2;      // off: N_NODES+1 (+pad)
    size_t oPs   = oOff + (size_t)(N_NODES + 32) * 4;   // psize: 512 ints
    size_t oSlab = oPs + 4096;                          // slabs: 512*4096*8B = 16.8 MB
    size_t oCsr  = oSlab + (size_t)NBIN * PCAP * 8;     // csr: 12.8 MB

    ushort_t*  WT    = (ushort_t*)(p + oW);
    uint_t*    H16   = (uint_t*)(p + oH);
    int*       off   = (int*)(p + oOff);
    int*       psize = (int*)(p + oPs);
    long long* slab  = (long long*)(p + oSlab);
    long long* csr   = (long long*)(p + oCsr);

    wt_init<<<65, 256, 0, stream>>>(W0, W1, W2, WT, psize);
    fused_p1_gemm<<<2075, 256, 0, stream>>>(rows, cols, vals, psize, slab,
                                            x, oh, WT, H16);
    pass2_sort<<<NBIN, 256, 0, stream>>>(slab, psize, off, csr);
    gather_kernel<<<N_NODES / 16, 256, 0, stream>>>(H16, off, csr, out);
}